// Round 4
// baseline (2049.716 us; speedup 1.0000x reference)
//
#include <hip/hip_runtime.h>
#include <hip/hip_bf16.h>

#define NN   100000
#define EE   3200000
#define INF  512
#define HIDF 256
#define OUTF 64
#define KSTEPS 10

typedef __attribute__((ext_vector_type(8))) short short8;
typedef __attribute__((ext_vector_type(4))) float floatx4;
typedef unsigned short ushort_t;

static __device__ inline short bf2s(__hip_bfloat16 h) {
    return __builtin_bit_cast(short, h);
}

// manual round-to-nearest-even f32 -> bf16 (finite inputs)
static __device__ inline unsigned f2bf(float f) {
    unsigned u = __float_as_uint(f);
    return (u + 0x7FFFu + ((u >> 16) & 1u)) >> 16;
}

static __device__ inline float b2f(unsigned u16) {
    return __uint_as_float(u16 << 16);
}

static __device__ inline int sb(unsigned u, int byte) {
    return (int)(signed char)((u >> (byte * 8)) & 0xFFu);
}

// ---------------- setup kernels ----------------

__global__ void zero_kernel(int* p, int n) {
    int i = blockIdx.x * 256 + threadIdx.x;
    if (i < n) p[i] = 0;
}

__global__ void count_kernel(const int* __restrict__ ei, int* __restrict__ counts) {
    int e = blockIdx.x * 256 + threadIdx.x;
    if (e < EE) atomicAdd(&counts[ei[EE + e]], 1);
}

__global__ void dinv_kernel(const int* __restrict__ counts, float* __restrict__ dinv) {
    int i = blockIdx.x * 256 + threadIdx.x;
    if (i < NN) dinv[i] = rsqrtf((float)(counts[i] + 1));  // +1 self loop
}

// chunk=256 exclusive scan, per-block
__global__ void scan1(const int* __restrict__ counts, int* __restrict__ offs,
                      int* __restrict__ partial) {
    __shared__ int s[256];
    int tid = threadIdx.x;
    int i = blockIdx.x * 256 + tid;
    int v = (i < NN) ? counts[i] : 0;
    s[tid] = v;
    __syncthreads();
    for (int d = 1; d < 256; d <<= 1) {
        int t = (tid >= d) ? s[tid - d] : 0;
        __syncthreads();
        s[tid] += t;
        __syncthreads();
    }
    if (i < NN) offs[i] = s[tid] - v;     // exclusive within block
    if (tid == 255) partial[blockIdx.x] = s[255];
}

__global__ void scan2(int* partial, int nblocks) {
    __shared__ int s[512];
    int tid = threadIdx.x;
    int v = (tid < nblocks) ? partial[tid] : 0;
    s[tid] = v;
    __syncthreads();
    for (int d = 1; d < 512; d <<= 1) {
        int t = (tid >= d) ? s[tid - d] : 0;
        __syncthreads();
        s[tid] += t;
        __syncthreads();
    }
    if (tid < nblocks) partial[tid] = s[tid] - v;  // exclusive block bases
}

__global__ void scan3(int* __restrict__ offs, const int* __restrict__ partial) {
    int i = blockIdx.x * 256 + threadIdx.x;
    if (i < NN) offs[i] += partial[i >> 8];
    else if (i == NN) offs[NN] = EE;
}

// cursor[i] = offs[i+1]  (fill counts down from segment end)
__global__ void prefill_kernel(const int* __restrict__ offs, int* __restrict__ cursor) {
    int i = blockIdx.x * 256 + threadIdx.x;
    if (i < NN) cursor[i] = offs[i + 1];
}

// countdown-fill, 1 edge per thread; atomic returns final position directly
__global__ void fill_kernel(const int* __restrict__ ei, int* __restrict__ cursor,
                            int* __restrict__ srcIdx) {
    int e = blockIdx.x * 256 + threadIdx.x;
    if (e >= EE) return;
    int r = ei[e];
    int c = ei[EE + e];
    int pos = atomicSub(&cursor[c], 1) - 1;
    srcIdx[pos] = r;
}

// pack W1 into per-lane MFMA B-fragment order
__global__ void pack_w1(const float* __restrict__ W1, short* __restrict__ W1p) {
    int id = blockIdx.x * 256 + threadIdx.x;
    if (id >= INF * HIDF) return;
    int jj = id & 7, l = (id >> 3) & 15, q = (id >> 7) & 3, t = (id >> 9) & 15, kk = id >> 13;
    int k = kk * 32 + q * 8 + jj, n = t * 16 + l;
    W1p[id] = (short)f2bf(W1[k * HIDF + n]);
}

__global__ void pack_w2(const float* __restrict__ W2, short* __restrict__ W2p) {
    int id = blockIdx.x * 256 + threadIdx.x;
    if (id >= HIDF * OUTF) return;
    int jj = id & 7, l = (id >> 3) & 15, q = (id >> 7) & 3, t = (id >> 9) & 3, kk = id >> 11;
    int k = kk * 32 + q * 8 + jj, n = t * 16 + l;
    W2p[id] = (short)f2bf(W2[k * OUTF + n]);
}

// ---------------- fused MLP: h = relu(x@W1+b1)@W2+b2 ----------------
// writes hb = bf16(h) and out = temp[0]*h

__global__ __launch_bounds__(256) void mlp_kernel(
    const float* __restrict__ x, const short* __restrict__ W1p,
    const short* __restrict__ W2p, const float* __restrict__ b1,
    const float* __restrict__ b2, const float* __restrict__ temp,
    ushort_t* __restrict__ hb, float* __restrict__ out) {

    __shared__ __align__(16) short hlds[64][HIDF + 8];

    int tid = threadIdx.x;
    int wave = tid >> 6, lane = tid & 63;
    int l16 = lane & 15, quad = lane >> 4;
    int brow = blockIdx.x * 64;

    const floatx4 zf = {0.f, 0.f, 0.f, 0.f};
    floatx4 acc[4][4];
#pragma unroll
    for (int mi = 0; mi < 4; mi++)
#pragma unroll
        for (int j = 0; j < 4; j++) acc[mi][j] = zf;

    const float* rp[4];
#pragma unroll
    for (int mi = 0; mi < 4; mi++) {
        int row = brow + mi * 16 + l16;
        if (row > NN - 1) row = NN - 1;
        rp[mi] = x + (size_t)row * INF + quad * 8;
    }

    for (int kk = 0; kk < 16; kk++) {
        short8 a[4];
#pragma unroll
        for (int mi = 0; mi < 4; mi++) {
            const float4* ap = reinterpret_cast<const float4*>(rp[mi] + kk * 32);
            float4 f0 = ap[0];
            float4 f1 = ap[1];
            __hip_bfloat162 q0 = __float22bfloat162_rn(make_float2(f0.x, f0.y));
            __hip_bfloat162 q1 = __float22bfloat162_rn(make_float2(f0.z, f0.w));
            __hip_bfloat162 q2 = __float22bfloat162_rn(make_float2(f1.x, f1.y));
            __hip_bfloat162 q3 = __float22bfloat162_rn(make_float2(f1.z, f1.w));
            short8 av;
            av[0] = bf2s(q0.x); av[1] = bf2s(q0.y);
            av[2] = bf2s(q1.x); av[3] = bf2s(q1.y);
            av[4] = bf2s(q2.x); av[5] = bf2s(q2.y);
            av[6] = bf2s(q3.x); av[7] = bf2s(q3.y);
            a[mi] = av;
        }
        short8 b[4];
#pragma unroll
        for (int j = 0; j < 4; j++) {
            int t = wave * 4 + j;
            b[j] = *reinterpret_cast<const short8*>(
                W1p + (((size_t)(kk * 16 + t) * 64 + quad * 16 + l16) << 3));
        }
#pragma unroll
        for (int mi = 0; mi < 4; mi++)
#pragma unroll
            for (int j = 0; j < 4; j++)
                acc[mi][j] = __builtin_amdgcn_mfma_f32_16x16x32_bf16(a[mi], b[j], acc[mi][j], 0, 0, 0);
    }

#pragma unroll
    for (int j = 0; j < 4; j++) {
        float bj = b1[wave * 64 + j * 16 + l16];
#pragma unroll
        for (int mi = 0; mi < 4; mi++)
#pragma unroll
            for (int r = 0; r < 4; r++) {
                float v = acc[mi][j][r] + bj;
                v = fmaxf(v, 0.f);
                hlds[mi * 16 + quad * 4 + r][wave * 64 + j * 16 + l16] = (short)f2bf(v);
            }
    }
    __syncthreads();

    floatx4 acc2[4];
#pragma unroll
    for (int j = 0; j < 4; j++) acc2[j] = zf;

#pragma unroll
    for (int kk = 0; kk < 8; kk++) {
        short8 a2 = *reinterpret_cast<const short8*>(&hlds[wave * 16 + l16][kk * 32 + quad * 8]);
#pragma unroll
        for (int j = 0; j < 4; j++) {
            short8 bb = *reinterpret_cast<const short8*>(
                W2p + (((size_t)(kk * 4 + j) * 64 + quad * 16 + l16) << 3));
            acc2[j] = __builtin_amdgcn_mfma_f32_16x16x32_bf16(a2, bb, acc2[j], 0, 0, 0);
        }
    }

    float t0 = temp[0];
#pragma unroll
    for (int j = 0; j < 4; j++) {
        float bb = b2[j * 16 + l16];
#pragma unroll
        for (int r = 0; r < 4; r++) {
            int row = brow + wave * 16 + quad * 4 + r;
            if (row < NN) {
                float v = acc2[j][r] + bb;
                size_t o = (size_t)row * 64 + j * 16 + l16;
                out[o] = t0 * v;
                hb[o] = (ushort_t)f2bf(v);
            }
        }
    }
}

// ---------------- quantize z0 = int8(dinv*h), per-node amax scale ----------
// 16 lanes per node; lane covers 4 features (uint2 of bf16)

__global__ __launch_bounds__(256) void quant_kernel(
    const ushort_t* __restrict__ hb, const float* __restrict__ dinv,
    unsigned* __restrict__ zq, float* __restrict__ zs) {

    int g = blockIdx.x * 256 + threadIdx.x;
    int node = g >> 4;
    int l16 = g & 15;
    if (node >= NN) return;

    const uint2 hh = *reinterpret_cast<const uint2*>(hb + (size_t)node * 64 + l16 * 4);
    float dv = dinv[node];
    float v0 = dv * b2f(hh.x & 0xFFFFu);
    float v1 = dv * b2f(hh.x >> 16);
    float v2 = dv * b2f(hh.y & 0xFFFFu);
    float v3 = dv * b2f(hh.y >> 16);

    float m = fmaxf(fmaxf(fabsf(v0), fabsf(v1)), fmaxf(fabsf(v2), fabsf(v3)));
    m = fmaxf(m, __shfl_xor(m, 1, 64));
    m = fmaxf(m, __shfl_xor(m, 2, 64));
    m = fmaxf(m, __shfl_xor(m, 4, 64));
    m = fmaxf(m, __shfl_xor(m, 8, 64));

    float si = (m > 0.f) ? 127.0f / m : 0.f;
    if (l16 == 0) zs[node] = m * (1.0f / 127.0f);

    int q0 = (int)rintf(v0 * si);
    int q1 = (int)rintf(v1 * si);
    int q2 = (int)rintf(v2 * si);
    int q3 = (int)rintf(v3 * si);
    zq[node * 16 + l16] = (unsigned)(q0 & 0xFF) | ((unsigned)(q1 & 0xFF) << 8) |
                          ((unsigned)(q2 & 0xFF) << 16) | ((unsigned)(q3 & 0xFF) << 24);
}

// ---------------- propagation ----------------
// z stored int8 (per-node scale): row = 64 B = 1 cache line.
// wave per node; quad handles edge e+quad; 16 lanes x uchar4 cover the row.
// acc = z[self] + sum z[src]; cur = dinv*acc; hid += gamma*cur;
// z' = int8-quantize(dinv*cur).

__global__ __launch_bounds__(256) void prop_kernel(
    const int* __restrict__ srcIdx, const int* __restrict__ offs,
    const float* __restrict__ dinv,
    const unsigned* __restrict__ zq, const float* __restrict__ zs,
    unsigned* __restrict__ zqn, float* __restrict__ zsn,
    float* __restrict__ hid, const float* __restrict__ temp, int k, int write_z) {

    int node = blockIdx.x * 4 + (threadIdx.x >> 6);
    int lane = threadIdx.x & 63;
    int l16 = lane & 15, quad = lane >> 4;

    int beg = __builtin_amdgcn_readfirstlane(offs[node]);
    int end = __builtin_amdgcn_readfirstlane(offs[node + 1]);

    float a0 = 0.f, a1 = 0.f, a2 = 0.f, a3 = 0.f;

    // self loop: quad 0 contributes (uniform control flow; others fma with 0)
    {
        unsigned u = zq[node * 16 + l16];
        float se = (quad == 0) ? zs[node] : 0.f;
        a0 = fmaf((float)sb(u, 0), se, a0);
        a1 = fmaf((float)sb(u, 1), se, a1);
        a2 = fmaf((float)sb(u, 2), se, a2);
        a3 = fmaf((float)sb(u, 3), se, a3);
    }

    for (int e = beg; e < end; e += 4) {
        int idx = e + quad;
        int cl = min(idx, end - 1);
        int src = srcIdx[cl];
        float se = (idx < end) ? zs[src] : 0.f;
        unsigned u = zq[src * 16 + l16];
        a0 = fmaf((float)sb(u, 0), se, a0);
        a1 = fmaf((float)sb(u, 1), se, a1);
        a2 = fmaf((float)sb(u, 2), se, a2);
        a3 = fmaf((float)sb(u, 3), se, a3);
    }

    // combine quads: lane gets sum over {l, l^16, l^32, l^48}
    a0 += __shfl_xor(a0, 16, 64); a0 += __shfl_xor(a0, 32, 64);
    a1 += __shfl_xor(a1, 16, 64); a1 += __shfl_xor(a1, 32, 64);
    a2 += __shfl_xor(a2, 16, 64); a2 += __shfl_xor(a2, 32, 64);
    a3 += __shfl_xor(a3, 16, 64); a3 += __shfl_xor(a3, 32, 64);

    if (quad == 0) {
        float dv = dinv[node];
        float c0 = dv * a0, c1 = dv * a1, c2 = dv * a2, c3 = dv * a3;
        float g = temp[k];
        float4* hp = reinterpret_cast<float4*>(hid + (size_t)node * 64 + l16 * 4);
        float4 h = *hp;
        h.x += g * c0; h.y += g * c1; h.z += g * c2; h.w += g * c3;
        *hp = h;

        if (write_z) {
            float z0f = dv * c0, z1f = dv * c1, z2f = dv * c2, z3f = dv * c3;
            float m = fmaxf(fmaxf(fabsf(z0f), fabsf(z1f)), fmaxf(fabsf(z2f), fabsf(z3f)));
            m = fmaxf(m, __shfl_xor(m, 1, 64));
            m = fmaxf(m, __shfl_xor(m, 2, 64));
            m = fmaxf(m, __shfl_xor(m, 4, 64));
            m = fmaxf(m, __shfl_xor(m, 8, 64));
            float si = (m > 0.f) ? 127.0f / m : 0.f;
            if (l16 == 0) zsn[node] = m * (1.0f / 127.0f);
            int q0 = (int)rintf(z0f * si);
            int q1 = (int)rintf(z1f * si);
            int q2 = (int)rintf(z2f * si);
            int q3 = (int)rintf(z3f * si);
            zqn[node * 16 + l16] = (unsigned)(q0 & 0xFF) | ((unsigned)(q1 & 0xFF) << 8) |
                                   ((unsigned)(q2 & 0xFF) << 16) | ((unsigned)(q3 & 0xFF) << 24);
        }
    }
}

// ---------------- launch ----------------

extern "C" void kernel_launch(void* const* d_in, const int* in_sizes, int n_in,
                              void* d_out, int out_size, void* d_ws, size_t ws_size,
                              hipStream_t stream) {
    const float* x    = (const float*)d_in[0];
    const int*   ei   = (const int*)d_in[1];
    const float* W1   = (const float*)d_in[2];
    const float* b1   = (const float*)d_in[3];
    const float* W2   = (const float*)d_in[4];
    const float* b2   = (const float*)d_in[5];
    const float* temp = (const float*)d_in[6];
    float* out = (float*)d_out;

    char* p = (char*)d_ws;
    auto carve = [&](size_t bytes) -> char* {
        char* r = p;
        p += (bytes + 255) & ~(size_t)255;
        return r;
    };
    unsigned* zqA  = (unsigned*)carve(sizeof(unsigned) * (size_t)NN * 16);
    unsigned* zqB  = (unsigned*)carve(sizeof(unsigned) * (size_t)NN * 16);
    float* zsA     = (float*)carve(sizeof(float) * NN);
    float* zsB     = (float*)carve(sizeof(float) * NN);
    ushort_t* hb   = (ushort_t*)carve(sizeof(ushort_t) * (size_t)NN * 64);
    int* srcIdx    = (int*)carve(sizeof(int) * (size_t)EE);
    int* counts    = (int*)carve(sizeof(int) * NN);
    int* cursor    = (int*)carve(sizeof(int) * NN);
    int* offs      = (int*)carve(sizeof(int) * (NN + 1));
    int* partial   = (int*)carve(sizeof(int) * 512);
    float* dinv    = (float*)carve(sizeof(float) * NN);
    short* W1p     = (short*)carve(sizeof(short) * INF * HIDF);
    short* W2p     = (short*)carve(sizeof(short) * HIDF * OUTF);

    const int NB = (NN + 255) / 256;      // 391

    zero_kernel<<<NB, 256, 0, stream>>>(counts, NN);
    pack_w1<<<(INF * HIDF + 255) / 256, 256, 0, stream>>>(W1, W1p);
    pack_w2<<<(HIDF * OUTF + 255) / 256, 256, 0, stream>>>(W2, W2p);

    count_kernel<<<EE / 256, 256, 0, stream>>>(ei, counts);
    dinv_kernel<<<NB, 256, 0, stream>>>(counts, dinv);
    scan1<<<NB, 256, 0, stream>>>(counts, offs, partial);
    scan2<<<1, 512, 0, stream>>>(partial, NB);
    scan3<<<(NN + 256) / 256, 256, 0, stream>>>(offs, partial);
    prefill_kernel<<<NB, 256, 0, stream>>>(offs, cursor);
    fill_kernel<<<EE / 256, 256, 0, stream>>>(ei, cursor, srcIdx);

    mlp_kernel<<<(NN + 63) / 64, 256, 0, stream>>>(x, W1p, W2p, b1, b2, temp, hb, out);
    quant_kernel<<<NN * 16 / 256, 256, 0, stream>>>(hb, dinv, zqA, zsA);

    unsigned* qa = zqA; unsigned* qb = zqB;
    float* sa = zsA;    float* sb_ = zsB;
    for (int k = 1; k <= KSTEPS; k++) {
        prop_kernel<<<NN / 4, 256, 0, stream>>>(srcIdx, offs, dinv, qa, sa, qb, sb_,
                                                out, temp, k, (k < KSTEPS) ? 1 : 0);
        unsigned* tq = qa; qa = qb; qb = tq;
        float* ts = sa; sa = sb_; sb_ = ts;
    }
}